// Round 14
// baseline (532.757 us; speedup 1.0000x reference)
//
#include <hip/hip_runtime.h>
#include <cstdint>
#include <cstddef>

#define BB 4
#define TT 16384
#define CC 512
#define HH 8
#define DD 64
#define MTOT (BB*TT)   // 65536 token rows

typedef __attribute__((ext_vector_type(4))) float f32x4;
typedef __bf16 bf16;
typedef __attribute__((ext_vector_type(8))) bf16 bf16x8;
typedef __attribute__((ext_vector_type(4))) bf16 bf16x4;

static __device__ __forceinline__ float b2f(bf16 x) { return (float)x; }
static __device__ __forceinline__ bf16  f2b(float x) { return (bf16)x; }

// async global->LDS, 16B per lane; dest = wave-uniform base + lane*16
static __device__ __forceinline__ void gload16(const bf16* src, bf16* ldsbase) {
    __builtin_amdgcn_global_load_lds(
        (const __attribute__((address_space(1))) void*)src,
        (__attribute__((address_space(3))) void*)ldsbase, 16, 0, 0);
}

// ---------------------------------------------------------------------------
// Transpose+convert all five 512x512 fp32 weights to bf16 Wt[n][k] = W[k][n].
// VERIFIED r6. grid = 5*256 x 256.
// ---------------------------------------------------------------------------
__global__ __launch_bounds__(256) void transpose_w5(
    const float* __restrict__ W0, const float* __restrict__ W1,
    const float* __restrict__ W2, const float* __restrict__ W3,
    const float* __restrict__ W4,
    bf16* __restrict__ T0, bf16* __restrict__ T1, bf16* __restrict__ T2,
    bf16* __restrict__ T3, bf16* __restrict__ T4)
{
    __shared__ float tile[32][33];
    const int which = blockIdx.x >> 8;
    const float* W = which == 0 ? W0 : which == 1 ? W1 : which == 2 ? W2
                   : which == 3 ? W3 : W4;
    bf16* Wt = which == 0 ? T0 : which == 1 ? T1 : which == 2 ? T2
             : which == 3 ? T3 : T4;
    const int t = blockIdx.x & 255;
    const int r0 = (t >> 4) * 32, c0 = (t & 15) * 32;
    const int tid = threadIdx.x;
    {
        int r = tid >> 3, c4 = (tid & 7) << 2;
        float4 v = *(const float4*)(W + (size_t)(r0 + r) * 512 + c0 + c4);
        tile[r][c4 + 0] = v.x; tile[r][c4 + 1] = v.y;
        tile[r][c4 + 2] = v.z; tile[r][c4 + 3] = v.w;
    }
    __syncthreads();
    {
        int n = tid >> 3, k4 = (tid & 7) << 2;
        bf16x4 o;
        o[0] = f2b(tile[k4 + 0][n]); o[1] = f2b(tile[k4 + 1][n]);
        o[2] = f2b(tile[k4 + 2][n]); o[3] = f2b(tile[k4 + 3][n]);
        *(bf16x4*)(Wt + (size_t)(c0 + n) * 512 + r0 + k4) = o;
    }
}

// ---------------------------------------------------------------------------
// Projection GEMM (MFMA), 2-DEEP PIPELINE v14.
// r12-verified shape/fragments/epilogue. Schedule: every load issued a FULL
// K-step before consumption:
//  - A: two named register sets (A(even)->aA, A(odd)->aB); writeA(t+1) runs
//    one step after its loads were issued -> no latency stall at the ds_write.
//    MODE3: A via gload into double-buffered Asm (r12-verified 1-gload/wave
//    map; fixes r13's OOB/racy MODE3 staging).
//  - B: triple-buffered, gload(t+2) issued at end of step t (2-step distance).
//  - counted vmcnt(6) (5 for MODE3) at step top; never 0 except last step.
// Reuse distances: Bsm[(t+2)%3] last read at step t-1 (pre-issue barrier);
// Asm[(t+1)&1] last read at step t-1. All issues occur after the post-MFMA
// barrier of the reading step -> race-free.
// MODE 0: fp32 A, fused per-head softmax, store bf16 (Q/K)
// MODE 2: dual fp32 A (K=1024), +bias0+bias1, store bf16 (V)
// MODE 3: bf16 A, +bias, store fp32 (final out; m_base for phased launches)
// ---------------------------------------------------------------------------
template<int MODE>
__global__ __launch_bounds__(512, 2) void gemm_proj(
    const float* A0, const float* A1, const bf16* Abf,
    const bf16* Wt0, const bf16* Wt1,
    const float* bias0, const float* bias1,
    bf16* outb, float* outf, int m_base)
{
    constexpr int ASTR = (MODE == 3) ? 32 : 40;
    constexpr int KSTEPS = (MODE == 2) ? 32 : 16;
    __shared__ bf16 Asm[2][128 * ASTR];   // 20 KB (16 KB MODE3)
    __shared__ bf16 Bsm[3][512 * 32];     // 96 KB

    const int tid = threadIdx.x;
    const int lane = tid & 63;
    const int w = tid >> 6;
    const int l15 = lane & 15, lg = lane >> 4;
    const int lq = lane >> 2, lc = lane & 3;       // gload lane map
    const size_t m0 = (size_t)(blockIdx.x + m_base) * 128;

    const int arow = tid >> 2, acol = (tid & 3) << 2;   // MODE0/2 A reg map

    f32x4 acc[8][4];
#pragma unroll
    for (int m = 0; m < 8; ++m)
#pragma unroll
        for (int n = 0; n < 4; ++n) acc[m][n] = (f32x4){0.f, 0.f, 0.f, 0.f};

    float4 aA0, aA1, aB0, aB1;   // A prefetch sets: A(even)->aA, A(odd)->aB

#define LOADA_REG(T, R0, R1) {                                                \
        const float* Af_ = (MODE == 2 && (T) >= 16) ? A1 : A0;                \
        R0 = *(const float4*)(Af_ + (m0 + arow) * CC + ((T) & 15) * 32 + acol);      \
        R1 = *(const float4*)(Af_ + (m0 + arow) * CC + ((T) & 15) * 32 + acol + 16); }
#define GLOADA(T) {                                                           \
        gload16(Abf + (m0 + w * 16 + lq) * CC + ((T) & 15) * 32 + lc * 8,     \
                &Asm[(T) & 1][(w * 16) * 32]); }
#define WRITEA(BUF, R0, R1) { bf16x4 s0_, s1_;                                \
        s0_[0] = f2b(R0.x); s0_[1] = f2b(R0.y);                               \
        s0_[2] = f2b(R0.z); s0_[3] = f2b(R0.w);                               \
        s1_[0] = f2b(R1.x); s1_[1] = f2b(R1.y);                               \
        s1_[2] = f2b(R1.z); s1_[3] = f2b(R1.w);                               \
        *(bf16x4*)&Asm[BUF][arow * 40 + acol] = s0_;                          \
        *(bf16x4*)&Asm[BUF][arow * 40 + acol + 16] = s1_; }
#define ISSUEB(T) { const bf16* Wt_ = (MODE == 2 && (T) >= 16) ? Wt1 : Wt0;   \
        _Pragma("unroll")                                                     \
        for (int r_ = 0; r_ < 4; ++r_) {                                      \
            int rowbase_ = r_ * 128 + w * 16;                                 \
            gload16(Wt_ + (size_t)(rowbase_ + lq) * CC + ((T) & 15) * 32 + lc * 8, \
                    &Bsm[(T) % 3][rowbase_ * 32]); } }
#define GSTEP(T, WA0, WA1, IA0, IA1) {                                        \
        if ((T) + 1 < KSTEPS) {                                               \
            if (MODE == 3) asm volatile("s_waitcnt vmcnt(5)" ::: "memory");   \
            else           asm volatile("s_waitcnt vmcnt(6)" ::: "memory");   \
        } else {                                                              \
            asm volatile("s_waitcnt vmcnt(0)" ::: "memory");                  \
        }                                                                     \
        __builtin_amdgcn_s_barrier();                                         \
        bf16x8 af_[8], bfv_[4];                                               \
        const bf16* As_ = &Asm[(T) & 1][0];                                   \
        const bf16* Bs_ = &Bsm[(T) % 3][0];                                   \
        _Pragma("unroll")                                                     \
        for (int m_ = 0; m_ < 8; ++m_)                                        \
            af_[m_] = *(const bf16x8*)&As_[(m_ * 16 + l15) * ASTR + lg * 8];  \
        _Pragma("unroll")                                                     \
        for (int n_ = 0; n_ < 4; ++n_)                                        \
            bfv_[n_] = *(const bf16x8*)&Bs_[(w * 64 + n_ * 16 + l15) * 32 + lg * 8]; \
        _Pragma("unroll")                                                     \
        for (int m_ = 0; m_ < 8; ++m_)                                        \
            _Pragma("unroll")                                                 \
            for (int n_ = 0; n_ < 4; ++n_)                                    \
                acc[m_][n_] = __builtin_amdgcn_mfma_f32_16x16x32_bf16(        \
                    af_[m_], bfv_[n_], acc[m_][n_], 0, 0, 0);                 \
        __builtin_amdgcn_s_barrier();                                         \
        if (MODE != 3 && (T) + 1 < KSTEPS) {                                  \
            WRITEA(((T) + 1) & 1, WA0, WA1);                                  \
            asm volatile("s_waitcnt lgkmcnt(0)" ::: "memory");                \
        }                                                                     \
        if ((T) + 2 < KSTEPS) {                                               \
            if (MODE == 3) { GLOADA((T) + 2); }                               \
            else { LOADA_REG((T) + 2, IA0, IA1); }                            \
            ISSUEB((T) + 2);                                                  \
        } }

    // ---- prologue: steps 0 and 1 in flight ----
    if (MODE == 3) {
        GLOADA(0); ISSUEB(0);
        GLOADA(1); ISSUEB(1);
    } else {
        LOADA_REG(0, aA0, aA1); ISSUEB(0);
        LOADA_REG(1, aB0, aB1); ISSUEB(1);
        WRITEA(0, aA0, aA1);    // waits A(0) regs only; B stays in flight
        asm volatile("s_waitcnt lgkmcnt(0)" ::: "memory");
    }

    for (int ko = 0; ko < KSTEPS; ko += 2) {
        GSTEP(ko,     aB0, aB1, aA0, aA1);   // write A(ko+1) [odd->aB]; issue A(ko+2)->aA
        GSTEP(ko + 1, aA0, aA1, aB0, aB1);   // write A(ko+2) [even->aA]; issue A(ko+3)->aB
    }
#undef LOADA_REG
#undef GLOADA
#undef WRITEA
#undef ISSUEB
#undef GSTEP

    // ---- epilogue (VERIFIED r6/r8/r9/r12 per-row math) ----
    float bias[4];
#pragma unroll
    for (int n = 0; n < 4; ++n) {
        int col = w * 64 + n * 16 + l15;
        float bvv = bias0 ? bias0[col] : 0.f;
        if (MODE == 2) bvv += bias1[col];
        bias[n] = bvv;
    }
#pragma unroll
    for (int m = 0; m < 8; ++m) {
#pragma unroll
        for (int reg = 0; reg < 4; ++reg) {
            int r = m * 16 + lg * 4 + reg;
            float v0 = acc[m][0][reg] + bias[0];
            float v1 = acc[m][1][reg] + bias[1];
            float v2 = acc[m][2][reg] + bias[2];
            float v3 = acc[m][3][reg] + bias[3];
            if (MODE == 0) {
                // softmax over this row's 64 head cols (16 lanes sharing lg)
                float mx = fmaxf(fmaxf(v0, v1), fmaxf(v2, v3));
#pragma unroll
                for (int s = 1; s < 16; s <<= 1) mx = fmaxf(mx, __shfl_xor(mx, s, 64));
                v0 = __expf(v0 - mx); v1 = __expf(v1 - mx);
                v2 = __expf(v2 - mx); v3 = __expf(v3 - mx);
                float sm = v0 + v1 + v2 + v3;
#pragma unroll
                for (int s = 1; s < 16; s <<= 1) sm += __shfl_xor(sm, s, 64);
                float inv = 1.0f / sm;
                v0 *= inv; v1 *= inv; v2 *= inv; v3 *= inv;
            }
            size_t rowoff = (m0 + r) * CC + w * 64 + l15;
            if (MODE == 3) {
                outf[rowoff + 0]  = v0; outf[rowoff + 16] = v1;
                outf[rowoff + 32] = v2; outf[rowoff + 48] = v3;
            } else {
                outb[rowoff + 0]  = f2b(v0); outb[rowoff + 16] = f2b(v1);
                outb[rowoff + 32] = f2b(v2); outb[rowoff + 48] = f2b(v3);
            }
        }
    }
}

// ---------------------------------------------------------------------------
// kv partials, scalar outer-product. VERIFIED r6. grid = 1024 x 256.
// ---------------------------------------------------------------------------
__global__ __launch_bounds__(256) void kv_partial2(
    const bf16* __restrict__ Kb, const bf16* __restrict__ Vb,
    float* __restrict__ part)
{
    __shared__ float Ks[32][68], Vs[32][68];
    const int tid = threadIdx.x;
    const int bh = blockIdx.x >> 5, chunk = blockIdx.x & 31;
    const int b = bh >> 3, h = bh & 7;
    const size_t base = (size_t)b * TT * CC + h * 64;
    const int d0 = (tid & 15) * 4, e0 = (tid >> 4) * 4;

    float acc[4][4];
#pragma unroll
    for (int i = 0; i < 4; ++i)
#pragma unroll
        for (int j = 0; j < 4; ++j) acc[i][j] = 0.f;
    float ks[4] = {0.f, 0.f, 0.f, 0.f};

    const int tstart = chunk * 512;
    for (int t0 = tstart; t0 < tstart + 512; t0 += 32) {
        __syncthreads();
#pragma unroll
        for (int rep = 0; rep < 2; ++rep) {
            int idx = (tid + rep * 256) * 4;           // [0, 2048)
            int t = idx >> 6, dc = idx & 63;           // t in [0,32)
            const bf16* gk = Kb + base + (size_t)(t0 + t) * CC + dc;
            const bf16* gv = Vb + base + (size_t)(t0 + t) * CC + dc;
            bf16x4 k4 = *(const bf16x4*)gk;
            bf16x4 v4 = *(const bf16x4*)gv;
            *(float4*)&Ks[t][dc] = make_float4(b2f(k4[0]), b2f(k4[1]), b2f(k4[2]), b2f(k4[3]));
            *(float4*)&Vs[t][dc] = make_float4(b2f(v4[0]), b2f(v4[1]), b2f(v4[2]), b2f(v4[3]));
        }
        __syncthreads();
#pragma unroll 8
        for (int tt = 0; tt < 32; ++tt) {
            float kf[4], vf[4];
#pragma unroll
            for (int i = 0; i < 4; ++i) { kf[i] = Ks[tt][d0 + i]; vf[i] = Vs[tt][e0 + i]; }
            if (e0 == 0) {
#pragma unroll
                for (int i = 0; i < 4; ++i) ks[i] += kf[i];
            }
#pragma unroll
            for (int i = 0; i < 4; ++i)
#pragma unroll
                for (int j = 0; j < 4; ++j) acc[i][j] += kf[i] * vf[j];
        }
    }

    float* p = part + (size_t)blockIdx.x * 4160;
#pragma unroll
    for (int i = 0; i < 4; ++i)
#pragma unroll
        for (int j = 0; j < 4; ++j) p[(d0 + i) * 64 + (e0 + j)] = acc[i][j];
    if (tid < 16) {
#pragma unroll
        for (int i = 0; i < 4; ++i) p[4096 + d0 + i] = ks[i];
    }
}

// ---------------------------------------------------------------------------
// Reduce 32 partials per (b,h) -> kvT fp32 [bh][e][d] + ksum.
// VERIFIED r11 (grid = 256: bh x 8 slices of 520 elems).
// ---------------------------------------------------------------------------
__global__ __launch_bounds__(256) void kv_reduce(
    const float* __restrict__ part, float* __restrict__ kvT,
    float* __restrict__ ksum)
{
    const int bh = blockIdx.x >> 3, sl = blockIdx.x & 7;
    const int tid = threadIdx.x;
    const float* p0 = part + (size_t)bh * 32 * 4160;
    const int i0 = sl * 520, i1 = i0 + 520;
    for (int i = i0 + tid; i < i1; i += 256) {
        float s = 0.f;
        for (int c = 0; c < 32; ++c) s += p0[(size_t)c * 4160 + i];
        if (i < 4096) {
            int d = i >> 6, e = i & 63;
            kvT[(size_t)bh * 4096 + e * 64 + d] = s;   // [e][d]
        } else {
            ksum[bh * 64 + (i - 4096)] = s;
        }
    }
}

// ---------------------------------------------------------------------------
// A' = (q @ kv) * 1/(q . ksum), scalar 4x4 tile, in place. VERIFIED r6.
// ---------------------------------------------------------------------------
__global__ __launch_bounds__(256) void qkv_norm2(
    bf16* Qb, const float* __restrict__ kvT, const float* __restrict__ ksum)
{
    __shared__ float Qs[64][68];    // [r][d]
    __shared__ float KVs[64][68];   // [d][e]
    __shared__ float ksm[8][64];
    const int tid = threadIdx.x;
    const size_t t0 = (size_t)blockIdx.x * 64;
    const int b = (int)(t0 / TT);
    const int rg = tid >> 4, cg = tid & 15;

    for (int i = tid; i < 512; i += 256) ksm[i >> 6][i & 63] = ksum[b * 512 + i];

    for (int h = 0; h < 8; ++h) {
        __syncthreads();
        const float* kvb = kvT + (size_t)(b * 8 + h) * 4096;
#pragma unroll
        for (int rep = 0; rep < 4; ++rep) {
            int idx = (tid + rep * 256) * 4;
            int rr = idx >> 6, dc = idx & 63;
            bf16x4 q4 = *(const bf16x4*)(Qb + (t0 + rr) * CC + h * 64 + dc);
            *(float4*)&Qs[rr][dc] = make_float4(b2f(q4[0]), b2f(q4[1]), b2f(q4[2]), b2f(q4[3]));
            float4 v4 = *(const float4*)(kvb + rr * 64 + dc);   // kvT[e][d] -> KVs[d][e]
            KVs[dc + 0][rr] = v4.x; KVs[dc + 1][rr] = v4.y;
            KVs[dc + 2][rr] = v4.z; KVs[dc + 3][rr] = v4.w;
        }
        __syncthreads();

        float acc[4][4];
#pragma unroll
        for (int i = 0; i < 4; ++i)
#pragma unroll
            for (int j = 0; j < 4; ++j) acc[i][j] = 0.f;
        float dot[4] = {0.f, 0.f, 0.f, 0.f};

        for (int d = 0; d < 64; ++d) {
            float ksd = ksm[h][d];
            float4 kv4 = *(const float4*)&KVs[d][cg * 4];
            float q[4];
#pragma unroll
            for (int i = 0; i < 4; ++i) {
                q[i] = Qs[rg * 4 + i][d];
                dot[i] += q[i] * ksd;
            }
#pragma unroll
            for (int i = 0; i < 4; ++i) {
                acc[i][0] += q[i] * kv4.x; acc[i][1] += q[i] * kv4.y;
                acc[i][2] += q[i] * kv4.z; acc[i][3] += q[i] * kv4.w;
            }
        }
#pragma unroll
        for (int i = 0; i < 4; ++i) {
            float dinv = 1.0f / dot[i];
            bf16x4 o;
#pragma unroll
            for (int j = 0; j < 4; ++j) o[j] = f2b(acc[i][j] * dinv);
            *(bf16x4*)(Qb + (t0 + rg * 4 + i) * CC + h * 64 + cg * 4) = o;
        }
    }
}

// ---------------------------------------------------------------------------
extern "C" void kernel_launch(void* const* d_in, const int* in_sizes, int n_in,
                              void* d_out, int out_size, void* d_ws, size_t ws_size,
                              hipStream_t stream)
{
    const float* x1 = (const float*)d_in[0];
    const float* x2 = (const float*)d_in[1];
    const float* y0 = (const float*)d_in[2];
    const float* y1 = (const float*)d_in[3];
    const float* Wq = (const float*)d_in[4];
    const float* bq = (const float*)d_in[5];
    const float* Wk = (const float*)d_in[6];
    const float* bk = (const float*)d_in[7];
    const float* Wv = (const float*)d_in[8];
    const float* bv = (const float*)d_in[9];
    const float* Wp = (const float*)d_in[10];
    const float* bp = (const float*)d_in[11];
    (void)in_sizes; (void)n_in; (void)out_size;

    char* ws = (char*)d_ws;
    size_t off = 0;
    auto alloc = [&](size_t bytes) -> void* {
        void* p = ws + off;
        off += (bytes + 255) & ~(size_t)255;
        return p;
    };
    bf16* WtQ  = (bf16*)alloc((size_t)512 * 512 * 2);
    bf16* WtK  = (bf16*)alloc((size_t)512 * 512 * 2);
    bf16* WtV0 = (bf16*)alloc((size_t)512 * 512 * 2);
    bf16* WtV1 = (bf16*)alloc((size_t)512 * 512 * 2);
    bf16* WtP  = (bf16*)alloc((size_t)512 * 512 * 2);
    float* ksum = (float*)alloc((size_t)32 * 64 * 4);
    float* kvT  = (float*)alloc((size_t)32 * 4096 * 4);
    float* part = (float*)alloc((size_t)1024 * 4160 * 4);
    bf16* Acopy = (bf16*)alloc((size_t)16 * 128 * CC * 2);  // fallback head copy

    const size_t QBYTES = (size_t)MTOT * CC * 2;            // 64 MB
    bf16* Qb_ws = nullptr;
    if (ws_size >= off + QBYTES + 256) Qb_ws = (bf16*)alloc(QBYTES);

    bf16* Kb = (bf16*)d_out;                          // 64 MB scratch in d_out
    bf16* Vb = Kb + (size_t)MTOT * CC;                // second 64 MB
    float* outF = (float*)d_out;

    transpose_w5<<<1280, 256, 0, stream>>>(Wq, Wk, Wv, Wv + (size_t)512 * 512, Wp,
                                           WtQ, WtK, WtV0, WtV1, WtP);

    gemm_proj<0><<<MTOT / 128, 512, 0, stream>>>(x2, nullptr, nullptr, WtK, nullptr,
                                                 bk, nullptr, Kb, nullptr, 0);
    gemm_proj<2><<<MTOT / 128, 512, 0, stream>>>(y0, y1, nullptr, WtV0, WtV1,
                                                 bv, bv + 512, Vb, nullptr, 0);
    kv_partial2<<<1024, 256, 0, stream>>>(Kb, Vb, part);
    kv_reduce<<<256, 256, 0, stream>>>(part, kvT, ksum);

    if (Qb_ws) {
        // Q/A' live in workspace: single final GEMM launch, no aliasing games.
        gemm_proj<0><<<MTOT / 128, 512, 0, stream>>>(x1, nullptr, nullptr, WtQ, nullptr,
                                                     bq, nullptr, Qb_ws, nullptr, 0);
        qkv_norm2<<<1024, 256, 0, stream>>>(Qb_ws, kvT, ksum);
        gemm_proj<3><<<MTOT / 128, 512, 0, stream>>>(nullptr, nullptr, (const bf16*)Qb_ws,
                                                     WtP, nullptr, bp, nullptr,
                                                     nullptr, outF, 0);
    } else {
        // Fallback (VERIFIED r8): Q aliases d_out; phased final + 2MB head copy.
        bf16* Qb = Kb;
        gemm_proj<0><<<MTOT / 128, 512, 0, stream>>>(x1, nullptr, nullptr, WtQ, nullptr,
                                                     bq, nullptr, Qb, nullptr, 0);
        qkv_norm2<<<1024, 256, 0, stream>>>(Qb, kvT, ksum);
        hipMemcpyAsync(Acopy, Qb, (size_t)16 * 128 * CC * 2, hipMemcpyDeviceToDevice,
                       stream);
        const int starts[5] = {256, 128, 64, 32, 16};
        const int counts[5] = {256, 128, 64, 32, 16};
        for (int p = 0; p < 5; ++p) {
            gemm_proj<3><<<counts[p], 512, 0, stream>>>(nullptr, nullptr, (const bf16*)Qb,
                                                        WtP, nullptr, bp, nullptr,
                                                        nullptr, outF, starts[p]);
        }
        gemm_proj<3><<<16, 512, 0, stream>>>(nullptr, nullptr, (const bf16*)Acopy,
                                             WtP, nullptr, bp, nullptr,
                                             nullptr, outF, 0);
    }
}

// Round 15
// 491.501 us; speedup vs baseline: 1.0839x; 1.0839x over previous
//
#include <hip/hip_runtime.h>
#include <cstdint>
#include <cstddef>

#define BB 4
#define TT 16384
#define CC 512
#define HH 8
#define DD 64
#define MTOT (BB*TT)   // 65536 token rows

typedef __attribute__((ext_vector_type(4))) float f32x4;
typedef __bf16 bf16;
typedef __attribute__((ext_vector_type(8))) bf16 bf16x8;
typedef __attribute__((ext_vector_type(4))) bf16 bf16x4;

static __device__ __forceinline__ float b2f(bf16 x) { return (float)x; }
static __device__ __forceinline__ bf16  f2b(float x) { return (bf16)x; }

// async global->LDS, 16B per lane; dest = wave-uniform base + lane*16
static __device__ __forceinline__ void gload16(const bf16* src, bf16* ldsbase) {
    __builtin_amdgcn_global_load_lds(
        (const __attribute__((address_space(1))) void*)src,
        (__attribute__((address_space(3))) void*)ldsbase, 16, 0, 0);
}

// ---------------------------------------------------------------------------
// Transpose+convert all five 512x512 fp32 weights to bf16 Wt[n][k] = W[k][n].
// VERIFIED r6. grid = 5*256 x 256.
// ---------------------------------------------------------------------------
__global__ __launch_bounds__(256) void transpose_w5(
    const float* __restrict__ W0, const float* __restrict__ W1,
    const float* __restrict__ W2, const float* __restrict__ W3,
    const float* __restrict__ W4,
    bf16* __restrict__ T0, bf16* __restrict__ T1, bf16* __restrict__ T2,
    bf16* __restrict__ T3, bf16* __restrict__ T4)
{
    __shared__ float tile[32][33];
    const int which = blockIdx.x >> 8;
    const float* W = which == 0 ? W0 : which == 1 ? W1 : which == 2 ? W2
                   : which == 3 ? W3 : W4;
    bf16* Wt = which == 0 ? T0 : which == 1 ? T1 : which == 2 ? T2
             : which == 3 ? T3 : T4;
    const int t = blockIdx.x & 255;
    const int r0 = (t >> 4) * 32, c0 = (t & 15) * 32;
    const int tid = threadIdx.x;
    {
        int r = tid >> 3, c4 = (tid & 7) << 2;
        float4 v = *(const float4*)(W + (size_t)(r0 + r) * 512 + c0 + c4);
        tile[r][c4 + 0] = v.x; tile[r][c4 + 1] = v.y;
        tile[r][c4 + 2] = v.z; tile[r][c4 + 3] = v.w;
    }
    __syncthreads();
    {
        int n = tid >> 3, k4 = (tid & 7) << 2;
        bf16x4 o;
        o[0] = f2b(tile[k4 + 0][n]); o[1] = f2b(tile[k4 + 1][n]);
        o[2] = f2b(tile[k4 + 2][n]); o[3] = f2b(tile[k4 + 3][n]);
        *(bf16x4*)(Wt + (size_t)(c0 + n) * 512 + r0 + k4) = o;
    }
}

// ---------------------------------------------------------------------------
// Projection GEMM (MFMA), BK=64 counted-vmcnt v15.
// r13-verified sync skeleton (issue@top -> vmcnt(N) -> barrier -> MFMA ->
// barrier -> writeA -> lgkm0), K-step doubled to BK=64 (half the barriers):
//  - A: reg-staged all modes into single-buffer [128][72] (padded, 2-way free).
//    MODE0/2: 4x float4 + cvt; MODE3: 2x bf16x8 copy.
//  - B: [2][512*64] via gload, rule-21 both-sides XOR swizzle (src col =
//    8*((l&7)^(l>>3)); read col ^= (l15&7)<<3) -> 2-way, conflict-free.
//  - per step: 64 MFMA/wave (2 kk-halves), vmcnt(12) (MODE3:10), never 0
//    except last step.
// MODE 0: fp32 A, fused per-head softmax, store bf16 (Q/K)
// MODE 2: dual fp32 A (K=1024), +bias0+bias1, store bf16 (V)
// MODE 3: bf16 A, +bias, store fp32 (final out; m_base for phased launches)
// ---------------------------------------------------------------------------
template<int MODE>
__global__ __launch_bounds__(512) void gemm_proj(
    const float* A0, const float* A1, const bf16* Abf,
    const bf16* Wt0, const bf16* Wt1,
    const float* bias0, const float* bias1,
    bf16* outb, float* outf, int m_base)
{
    constexpr int KSTEPS = (MODE == 2) ? 16 : 8;   // BK=64
    __shared__ bf16 Asm[128 * 72];     // 18 KB, padded
    __shared__ bf16 Bsm[2][512 * 64];  // 128 KB, swizzled layout

    const int tid = threadIdx.x;
    const int lane = tid & 63;
    const int w = tid >> 6;
    const int l15 = lane & 15, lg = lane >> 4;
    const size_t m0 = (size_t)(blockIdx.x + m_base) * 128;

    // A staging map: thread -> row tid>>2, 16 elems at (tid&3)*16
    const int arow = tid >> 2, ac16 = (tid & 3) << 4;
    // B gload lane map (swizzled source): row lr = lane>>3, col 8*((l&7)^lr)
    const int blr = lane >> 3;
    const int bsc = ((lane & 7) ^ blr) << 3;

    f32x4 acc[8][4];
#pragma unroll
    for (int m = 0; m < 8; ++m)
#pragma unroll
        for (int n = 0; n < 4; ++n) acc[m][n] = (f32x4){0.f, 0.f, 0.f, 0.f};

    float4 apf[4];   // fp32 A prefetch (MODE0/2)
    bf16x8 apb[2];   // bf16 A prefetch (MODE3)

    auto issueA = [&](int t) {
        if (MODE == 3) {
#pragma unroll
            for (int j = 0; j < 2; ++j)
                apb[j] = *(const bf16x8*)(Abf + (m0 + arow) * CC + (t & 7) * 64
                                          + ac16 + j * 8);
        } else {
            const float* Af = (MODE == 2 && t >= 8) ? A1 : A0;
#pragma unroll
            for (int j = 0; j < 4; ++j)
                apf[j] = *(const float4*)(Af + (m0 + arow) * CC + (t & 7) * 64
                                          + ac16 + j * 4);
        }
    };
    auto writeA = [&]() {
        if (MODE == 3) {
#pragma unroll
            for (int j = 0; j < 2; ++j)
                *(bf16x8*)&Asm[arow * 72 + ac16 + j * 8] = apb[j];
        } else {
#pragma unroll
            for (int j = 0; j < 4; ++j) {
                bf16x4 s;
                s[0] = f2b(apf[j].x); s[1] = f2b(apf[j].y);
                s[2] = f2b(apf[j].z); s[3] = f2b(apf[j].w);
                *(bf16x4*)&Asm[arow * 72 + ac16 + j * 4] = s;
            }
        }
    };
    auto issueB = [&](int t, int buf) {   // 8 gloads/wave, pre-swizzled source
        const bf16* Wt = (MODE == 2 && t >= 8) ? Wt1 : Wt0;
#pragma unroll
        for (int g = 0; g < 8; ++g) {
            int rowbase = w * 64 + g * 8;         // multiple of 8
            gload16(Wt + (size_t)(rowbase + blr) * CC + (t & 7) * 64 + bsc,
                    &Bsm[buf][rowbase * 64]);
        }
    };

    // ---- prologue: step 0 in flight ----
    issueA(0);
    issueB(0, 0);
    writeA();    // compiler waits A-regs precisely; B(0) gloads stay in flight
    asm volatile("s_waitcnt lgkmcnt(0)" ::: "memory");

    int cur = 0;
    for (int ko = 0; ko < KSTEPS; ++ko) {
        const bool more = ko + 1 < KSTEPS;
        if (more) { issueA(ko + 1); issueB(ko + 1, cur ^ 1); }
        // wait step-t's B; step t+1's (A:4/2 + B:8) stay in flight
        if (more) {
            if (MODE == 3) asm volatile("s_waitcnt vmcnt(10)" ::: "memory");
            else           asm volatile("s_waitcnt vmcnt(12)" ::: "memory");
        } else {
            asm volatile("s_waitcnt vmcnt(0)" ::: "memory");
        }
        __builtin_amdgcn_s_barrier();
        bf16x8 af[8][2], bfv[4][2];
#pragma unroll
        for (int m = 0; m < 8; ++m)
#pragma unroll
            for (int kk = 0; kk < 2; ++kk)
                af[m][kk] = *(const bf16x8*)&Asm[(m * 16 + l15) * 72 + kk * 32 + lg * 8];
#pragma unroll
        for (int n = 0; n < 4; ++n) {
            int row = w * 64 + n * 16 + l15;
            int swz = (l15 & 7) << 3;
#pragma unroll
            for (int kk = 0; kk < 2; ++kk)
                bfv[n][kk] = *(const bf16x8*)&Bsm[cur][row * 64
                                                      + ((kk * 32 + lg * 8) ^ swz)];
        }
#pragma unroll
        for (int kk = 0; kk < 2; ++kk)
#pragma unroll
            for (int m = 0; m < 8; ++m)
#pragma unroll
                for (int n = 0; n < 4; ++n)
                    acc[m][n] = __builtin_amdgcn_mfma_f32_16x16x32_bf16(
                        af[m][kk], bfv[n][kk], acc[m][n], 0, 0, 0);
        __builtin_amdgcn_s_barrier();   // all waves done reading Asm/Bsm[cur]
        if (more) {
            writeA();
            asm volatile("s_waitcnt lgkmcnt(0)" ::: "memory");
        }
        cur ^= 1;
    }

    // ---- epilogue (VERIFIED r6/r8/r9/r12 per-row math) ----
    float bias[4];
#pragma unroll
    for (int n = 0; n < 4; ++n) {
        int col = w * 64 + n * 16 + l15;
        float bvv = bias0 ? bias0[col] : 0.f;
        if (MODE == 2) bvv += bias1[col];
        bias[n] = bvv;
    }
#pragma unroll
    for (int m = 0; m < 8; ++m) {
#pragma unroll
        for (int reg = 0; reg < 4; ++reg) {
            int r = m * 16 + lg * 4 + reg;
            float v0 = acc[m][0][reg] + bias[0];
            float v1 = acc[m][1][reg] + bias[1];
            float v2 = acc[m][2][reg] + bias[2];
            float v3 = acc[m][3][reg] + bias[3];
            if (MODE == 0) {
                // softmax over this row's 64 head cols (16 lanes sharing lg)
                float mx = fmaxf(fmaxf(v0, v1), fmaxf(v2, v3));
#pragma unroll
                for (int s = 1; s < 16; s <<= 1) mx = fmaxf(mx, __shfl_xor(mx, s, 64));
                v0 = __expf(v0 - mx); v1 = __expf(v1 - mx);
                v2 = __expf(v2 - mx); v3 = __expf(v3 - mx);
                float sm = v0 + v1 + v2 + v3;
#pragma unroll
                for (int s = 1; s < 16; s <<= 1) sm += __shfl_xor(sm, s, 64);
                float inv = 1.0f / sm;
                v0 *= inv; v1 *= inv; v2 *= inv; v3 *= inv;
            }
            size_t rowoff = (m0 + r) * CC + w * 64 + l15;
            if (MODE == 3) {
                outf[rowoff + 0]  = v0; outf[rowoff + 16] = v1;
                outf[rowoff + 32] = v2; outf[rowoff + 48] = v3;
            } else {
                outb[rowoff + 0]  = f2b(v0); outb[rowoff + 16] = f2b(v1);
                outb[rowoff + 32] = f2b(v2); outb[rowoff + 48] = f2b(v3);
            }
        }
    }
}

// ---------------------------------------------------------------------------
// kv partials, scalar outer-product. VERIFIED r6. grid = 1024 x 256.
// ---------------------------------------------------------------------------
__global__ __launch_bounds__(256) void kv_partial2(
    const bf16* __restrict__ Kb, const bf16* __restrict__ Vb,
    float* __restrict__ part)
{
    __shared__ float Ks[32][68], Vs[32][68];
    const int tid = threadIdx.x;
    const int bh = blockIdx.x >> 5, chunk = blockIdx.x & 31;
    const int b = bh >> 3, h = bh & 7;
    const size_t base = (size_t)b * TT * CC + h * 64;
    const int d0 = (tid & 15) * 4, e0 = (tid >> 4) * 4;

    float acc[4][4];
#pragma unroll
    for (int i = 0; i < 4; ++i)
#pragma unroll
        for (int j = 0; j < 4; ++j) acc[i][j] = 0.f;
    float ks[4] = {0.f, 0.f, 0.f, 0.f};

    const int tstart = chunk * 512;
    for (int t0 = tstart; t0 < tstart + 512; t0 += 32) {
        __syncthreads();
#pragma unroll
        for (int rep = 0; rep < 2; ++rep) {
            int idx = (tid + rep * 256) * 4;           // [0, 2048)
            int t = idx >> 6, dc = idx & 63;           // t in [0,32)
            const bf16* gk = Kb + base + (size_t)(t0 + t) * CC + dc;
            const bf16* gv = Vb + base + (size_t)(t0 + t) * CC + dc;
            bf16x4 k4 = *(const bf16x4*)gk;
            bf16x4 v4 = *(const bf16x4*)gv;
            *(float4*)&Ks[t][dc] = make_float4(b2f(k4[0]), b2f(k4[1]), b2f(k4[2]), b2f(k4[3]));
            *(float4*)&Vs[t][dc] = make_float4(b2f(v4[0]), b2f(v4[1]), b2f(v4[2]), b2f(v4[3]));
        }
        __syncthreads();
#pragma unroll 8
        for (int tt = 0; tt < 32; ++tt) {
            float kf[4], vf[4];
#pragma unroll
            for (int i = 0; i < 4; ++i) { kf[i] = Ks[tt][d0 + i]; vf[i] = Vs[tt][e0 + i]; }
            if (e0 == 0) {
#pragma unroll
                for (int i = 0; i < 4; ++i) ks[i] += kf[i];
            }
#pragma unroll
            for (int i = 0; i < 4; ++i)
#pragma unroll
                for (int j = 0; j < 4; ++j) acc[i][j] += kf[i] * vf[j];
        }
    }

    float* p = part + (size_t)blockIdx.x * 4160;
#pragma unroll
    for (int i = 0; i < 4; ++i)
#pragma unroll
        for (int j = 0; j < 4; ++j) p[(d0 + i) * 64 + (e0 + j)] = acc[i][j];
    if (tid < 16) {
#pragma unroll
        for (int i = 0; i < 4; ++i) p[4096 + d0 + i] = ks[i];
    }
}

// ---------------------------------------------------------------------------
// Reduce 32 partials per (b,h) -> kvT fp32 [bh][e][d] + ksum.
// VERIFIED r11 (grid = 256: bh x 8 slices of 520 elems).
// ---------------------------------------------------------------------------
__global__ __launch_bounds__(256) void kv_reduce(
    const float* __restrict__ part, float* __restrict__ kvT,
    float* __restrict__ ksum)
{
    const int bh = blockIdx.x >> 3, sl = blockIdx.x & 7;
    const int tid = threadIdx.x;
    const float* p0 = part + (size_t)bh * 32 * 4160;
    const int i0 = sl * 520, i1 = i0 + 520;
    for (int i = i0 + tid; i < i1; i += 256) {
        float s = 0.f;
        for (int c = 0; c < 32; ++c) s += p0[(size_t)c * 4160 + i];
        if (i < 4096) {
            int d = i >> 6, e = i & 63;
            kvT[(size_t)bh * 4096 + e * 64 + d] = s;   // [e][d]
        } else {
            ksum[bh * 64 + (i - 4096)] = s;
        }
    }
}

// ---------------------------------------------------------------------------
// A' = (q @ kv) * 1/(q . ksum), scalar 4x4 tile, in place. VERIFIED r6.
// ---------------------------------------------------------------------------
__global__ __launch_bounds__(256) void qkv_norm2(
    bf16* Qb, const float* __restrict__ kvT, const float* __restrict__ ksum)
{
    __shared__ float Qs[64][68];    // [r][d]
    __shared__ float KVs[64][68];   // [d][e]
    __shared__ float ksm[8][64];
    const int tid = threadIdx.x;
    const size_t t0 = (size_t)blockIdx.x * 64;
    const int b = (int)(t0 / TT);
    const int rg = tid >> 4, cg = tid & 15;

    for (int i = tid; i < 512; i += 256) ksm[i >> 6][i & 63] = ksum[b * 512 + i];

    for (int h = 0; h < 8; ++h) {
        __syncthreads();
        const float* kvb = kvT + (size_t)(b * 8 + h) * 4096;
#pragma unroll
        for (int rep = 0; rep < 4; ++rep) {
            int idx = (tid + rep * 256) * 4;
            int rr = idx >> 6, dc = idx & 63;
            bf16x4 q4 = *(const bf16x4*)(Qb + (t0 + rr) * CC + h * 64 + dc);
            *(float4*)&Qs[rr][dc] = make_float4(b2f(q4[0]), b2f(q4[1]), b2f(q4[2]), b2f(q4[3]));
            float4 v4 = *(const float4*)(kvb + rr * 64 + dc);   // kvT[e][d] -> KVs[d][e]
            KVs[dc + 0][rr] = v4.x; KVs[dc + 1][rr] = v4.y;
            KVs[dc + 2][rr] = v4.z; KVs[dc + 3][rr] = v4.w;
        }
        __syncthreads();

        float acc[4][4];
#pragma unroll
        for (int i = 0; i < 4; ++i)
#pragma unroll
            for (int j = 0; j < 4; ++j) acc[i][j] = 0.f;
        float dot[4] = {0.f, 0.f, 0.f, 0.f};

        for (int d = 0; d < 64; ++d) {
            float ksd = ksm[h][d];
            float4 kv4 = *(const float4*)&KVs[d][cg * 4];
            float q[4];
#pragma unroll
            for (int i = 0; i < 4; ++i) {
                q[i] = Qs[rg * 4 + i][d];
                dot[i] += q[i] * ksd;
            }
#pragma unroll
            for (int i = 0; i < 4; ++i) {
                acc[i][0] += q[i] * kv4.x; acc[i][1] += q[i] * kv4.y;
                acc[i][2] += q[i] * kv4.z; acc[i][3] += q[i] * kv4.w;
            }
        }
#pragma unroll
        for (int i = 0; i < 4; ++i) {
            float dinv = 1.0f / dot[i];
            bf16x4 o;
#pragma unroll
            for (int j = 0; j < 4; ++j) o[j] = f2b(acc[i][j] * dinv);
            *(bf16x4*)(Qb + (t0 + rg * 4 + i) * CC + h * 64 + cg * 4) = o;
        }
    }
}

// ---------------------------------------------------------------------------
extern "C" void kernel_launch(void* const* d_in, const int* in_sizes, int n_in,
                              void* d_out, int out_size, void* d_ws, size_t ws_size,
                              hipStream_t stream)
{
    const float* x1 = (const float*)d_in[0];
    const float* x2 = (const float*)d_in[1];
    const float* y0 = (const float*)d_in[2];
    const float* y1 = (const float*)d_in[3];
    const float* Wq = (const float*)d_in[4];
    const float* bq = (const float*)d_in[5];
    const float* Wk = (const float*)d_in[6];
    const float* bk = (const float*)d_in[7];
    const float* Wv = (const float*)d_in[8];
    const float* bv = (const float*)d_in[9];
    const float* Wp = (const float*)d_in[10];
    const float* bp = (const float*)d_in[11];
    (void)in_sizes; (void)n_in; (void)out_size;

    char* ws = (char*)d_ws;
    size_t off = 0;
    auto alloc = [&](size_t bytes) -> void* {
        void* p = ws + off;
        off += (bytes + 255) & ~(size_t)255;
        return p;
    };
    bf16* WtQ  = (bf16*)alloc((size_t)512 * 512 * 2);
    bf16* WtK  = (bf16*)alloc((size_t)512 * 512 * 2);
    bf16* WtV0 = (bf16*)alloc((size_t)512 * 512 * 2);
    bf16* WtV1 = (bf16*)alloc((size_t)512 * 512 * 2);
    bf16* WtP  = (bf16*)alloc((size_t)512 * 512 * 2);
    float* ksum = (float*)alloc((size_t)32 * 64 * 4);
    float* kvT  = (float*)alloc((size_t)32 * 4096 * 4);
    float* part = (float*)alloc((size_t)1024 * 4160 * 4);
    bf16* Acopy = (bf16*)alloc((size_t)16 * 128 * CC * 2);  // fallback head copy

    const size_t QBYTES = (size_t)MTOT * CC * 2;            // 64 MB
    bf16* Qb_ws = nullptr;
    if (ws_size >= off + QBYTES + 256) Qb_ws = (bf16*)alloc(QBYTES);

    bf16* Kb = (bf16*)d_out;                          // 64 MB scratch in d_out
    bf16* Vb = Kb + (size_t)MTOT * CC;                // second 64 MB
    float* outF = (float*)d_out;

    transpose_w5<<<1280, 256, 0, stream>>>(Wq, Wk, Wv, Wv + (size_t)512 * 512, Wp,
                                           WtQ, WtK, WtV0, WtV1, WtP);

    gemm_proj<0><<<MTOT / 128, 512, 0, stream>>>(x2, nullptr, nullptr, WtK, nullptr,
                                                 bk, nullptr, Kb, nullptr, 0);
    gemm_proj<2><<<MTOT / 128, 512, 0, stream>>>(y0, y1, nullptr, WtV0, WtV1,
                                                 bv, bv + 512, Vb, nullptr, 0);
    kv_partial2<<<1024, 256, 0, stream>>>(Kb, Vb, part);
    kv_reduce<<<256, 256, 0, stream>>>(part, kvT, ksum);

    if (Qb_ws) {
        // Q/A' live in workspace: single final GEMM launch, no aliasing games.
        gemm_proj<0><<<MTOT / 128, 512, 0, stream>>>(x1, nullptr, nullptr, WtQ, nullptr,
                                                     bq, nullptr, Qb_ws, nullptr, 0);
        qkv_norm2<<<1024, 256, 0, stream>>>(Qb_ws, kvT, ksum);
        gemm_proj<3><<<MTOT / 128, 512, 0, stream>>>(nullptr, nullptr, (const bf16*)Qb_ws,
                                                     WtP, nullptr, bp, nullptr,
                                                     nullptr, outF, 0);
    } else {
        // Fallback (VERIFIED r8): Q aliases d_out; phased final + 2MB head copy.
        bf16* Qb = Kb;
        gemm_proj<0><<<MTOT / 128, 512, 0, stream>>>(x1, nullptr, nullptr, WtQ, nullptr,
                                                     bq, nullptr, Qb, nullptr, 0);
        qkv_norm2<<<1024, 256, 0, stream>>>(Qb, kvT, ksum);
        hipMemcpyAsync(Acopy, Qb, (size_t)16 * 128 * CC * 2, hipMemcpyDeviceToDevice,
                       stream);
        const int starts[5] = {256, 128, 64, 32, 16};
        const int counts[5] = {256, 128, 64, 32, 16};
        for (int p = 0; p < 5; ++p) {
            gemm_proj<3><<<counts[p], 512, 0, stream>>>(nullptr, nullptr, (const bf16*)Qb,
                                                        WtP, nullptr, bp, nullptr,
                                                        nullptr, outF, starts[p]);
        }
        gemm_proj<3><<<16, 512, 0, stream>>>(nullptr, nullptr, (const bf16*)Acopy,
                                             WtP, nullptr, bp, nullptr,
                                             nullptr, outF, 0);
    }
}